// Round 4
// baseline (394.872 us; speedup 1.0000x reference)
//
#include <hip/hip_runtime.h>
#include <math.h>

#define BATCH   64
#define NFEAT   256
#define GS      4
#define NG      64
#define WH      3136            // 56*56
#define PLANEQ  784             // WH/4 (float4 quads per channel plane)
#define NTOT    (BATCH*WH)      // 200704 samples per channel
#define EPSV    1e-3
#define PREC    16              // padded floats per partial record

typedef float vf4 __attribute__((ext_vector_type(4)));

// ---------------- Stage 1+2 fused: per-(b,g) partial sums, last block
// per group runs the eigen solve. Partial record (g*64+b)*16 + q, q<14:
//   q 0..3  = sum x_i ; q 4..13 = sum x_i x_j (i<=j)
// wm[g*24]: W(16), negWm(4), m(4).
__global__ __launch_bounds__(256) void wh_reduce_eigen(const float* __restrict__ x,
                                                       float* __restrict__ partials,
                                                       float* __restrict__ wm,
                                                       int* __restrict__ cnt) {
    const int blk = blockIdx.x;
    const int b = blk >> 6;
    const int g = blk & 63;
    const int tid = threadIdx.x;
    const vf4* __restrict__ xin =
        (const vf4*)(x + (size_t)b * ((size_t)NFEAT * WH) + (size_t)g * (GS * WH));

    // ---- 3 full iterations + 16-thread tail, loads issued up front ----
    vf4 a0 = xin[tid];             vf4 a1 = xin[tid + 256];             vf4 a2 = xin[tid + 512];
    vf4 b0 = xin[PLANEQ + tid];    vf4 b1 = xin[PLANEQ + tid + 256];    vf4 b2 = xin[PLANEQ + tid + 512];
    vf4 c0 = xin[2*PLANEQ + tid];  vf4 c1 = xin[2*PLANEQ + tid + 256];  vf4 c2 = xin[2*PLANEQ + tid + 512];
    vf4 d0 = xin[3*PLANEQ + tid];  vf4 d1 = xin[3*PLANEQ + tid + 256];  vf4 d2 = xin[3*PLANEQ + tid + 512];

    float s0=0.f,s1=0.f,s2=0.f,s3=0.f;
    float p0=0.f,p1=0.f,p2=0.f,p3=0.f,p4=0.f,p5=0.f,p6=0.f,p7=0.f,p8=0.f,p9=0.f;

#define ACC4(va, vb, vc, vd)                                         \
    {                                                                \
        _Pragma("unroll")                                            \
        for (int k = 0; k < 4; ++k) {                                \
            float A = (va)[k], B = (vb)[k], C = (vc)[k], D = (vd)[k];\
            s0 += A; s1 += B; s2 += C; s3 += D;                      \
            p0 = fmaf(A, A, p0);  p1 = fmaf(A, B, p1);               \
            p2 = fmaf(A, C, p2);  p3 = fmaf(A, D, p3);               \
            p4 = fmaf(B, B, p4);  p5 = fmaf(B, C, p5);               \
            p6 = fmaf(B, D, p6);  p7 = fmaf(C, C, p7);               \
            p8 = fmaf(C, D, p8);  p9 = fmaf(D, D, p9);               \
        }                                                            \
    }

    ACC4(a0, b0, c0, d0);
    ACC4(a1, b1, c1, d1);
    ACC4(a2, b2, c2, d2);
    if (tid < PLANEQ - 768) {   // 16 tail quads
        vf4 at = xin[768 + tid];
        vf4 bt = xin[PLANEQ + 768 + tid];
        vf4 ct = xin[2*PLANEQ + 768 + tid];
        vf4 dt = xin[3*PLANEQ + 768 + tid];
        ACC4(at, bt, ct, dt);
    }
#undef ACC4

    float vals[14] = {s0,s1,s2,s3,p0,p1,p2,p3,p4,p5,p6,p7,p8,p9};
    #pragma unroll
    for (int q = 0; q < 14; ++q) {
        float v = vals[q];
        #pragma unroll
        for (int off = 32; off > 0; off >>= 1) v += __shfl_down(v, off, 64);
        vals[q] = v;
    }

    __shared__ float lds[4][14];
    __shared__ int isLast;
    const int wave = tid >> 6;
    const int lane = tid & 63;
    if (lane == 0) {
        #pragma unroll
        for (int q = 0; q < 14; ++q) lds[wave][q] = vals[q];
    }
    __syncthreads();
    if (tid < 14) {
        float v = lds[0][tid] + lds[1][tid] + lds[2][tid] + lds[3][tid];
        partials[((size_t)(g * BATCH + b)) * PREC + tid] = v;
    }
    __threadfence();            // make partials visible device-wide
    __syncthreads();
    if (tid == 0) {
        int prev = atomicAdd(&cnt[g], 1);
        isLast = (prev == BATCH - 1);
    }
    __syncthreads();
    if (!isLast || tid >= 64) return;

    // ---- last block for this group: eigen solve on wave 0 ----
    __threadfence();            // acquire: see all groups' partials

    const float* base = partials + ((size_t)(g * BATCH + tid)) * PREC;
    double acc[14];
    #pragma unroll
    for (int q = 0; q < 14; ++q) acc[q] = (double)base[q];

    #pragma unroll
    for (int off = 32; off > 0; off >>= 1) {
        #pragma unroll
        for (int q = 0; q < 14; ++q) acc[q] += __shfl_xor(acc[q], off, 64);
    }

    if (tid != 0) return;

    const double n = (double)NTOT;
    double m[4];
    #pragma unroll
    for (int i = 0; i < 4; ++i) m[i] = acc[i] / n;

    const int pi[10] = {0,0,0,0,1,1,1,2,2,3};
    const int pj[10] = {0,1,2,3,1,2,3,2,3,3};

    double A[4][4];
    #pragma unroll
    for (int t = 0; t < 10; ++t) {
        double cov = acc[4 + t] - n * m[pi[t]] * m[pj[t]];
        double v = (1.0 - EPSV) * cov + ((pi[t] == pj[t]) ? EPSV : 0.0);
        A[pi[t]][pj[t]] = v;
        A[pj[t]][pi[t]] = v;
    }

    double V[4][4] = {{1,0,0,0},{0,1,0,0},{0,0,1,0},{0,0,0,1}};

    const double tr = A[0][0] + A[1][1] + A[2][2] + A[3][3];
    const double tol = 1e-26 * tr * tr + 1e-300;

    const int rp[6] = {0,0,0,1,1,2};
    const int rq[6] = {1,2,3,2,3,3};

    for (int sweep = 0; sweep < 10; ++sweep) {
        double off = 0.0;
        #pragma unroll
        for (int t = 0; t < 6; ++t) off += A[rp[t]][rq[t]] * A[rp[t]][rq[t]];
        if (off < tol) break;

        #pragma unroll
        for (int t = 0; t < 6; ++t) {
            const int p = rp[t], q = rq[t];
            double apq = A[p][q];
            if (apq * apq < 1e-60) continue;
            double theta = (A[q][q] - A[p][p]) / (2.0 * apq);
            double tt = ((theta >= 0.0) ? 1.0 : -1.0) /
                        (fabs(theta) + sqrt(theta * theta + 1.0));
            double c = 1.0 / sqrt(tt * tt + 1.0);
            double s = tt * c;
            #pragma unroll
            for (int k = 0; k < 4; ++k) {
                double akp = A[k][p], akq = A[k][q];
                A[k][p] = c * akp - s * akq;
                A[k][q] = s * akp + c * akq;
            }
            #pragma unroll
            for (int k = 0; k < 4; ++k) {
                double apk = A[p][k], aqk = A[q][k];
                A[p][k] = c * apk - s * aqk;
                A[q][k] = s * apk + c * aqk;
            }
            #pragma unroll
            for (int k = 0; k < 4; ++k) {
                double vkp = V[k][p], vkq = V[k][q];
                V[k][p] = c * vkp - s * vkq;
                V[k][q] = s * vkp + c * vkq;
            }
        }
    }

    double isq[4];
    #pragma unroll
    for (int k = 0; k < 4; ++k) isq[k] = 1.0 / sqrt(A[k][k] + EPSV);

    float* wo = wm + g * 24;
    double Wd[4][4];
    #pragma unroll
    for (int i = 0; i < 4; ++i) {
        #pragma unroll
        for (int j = 0; j < 4; ++j) {
            double w = 0.0;
            #pragma unroll
            for (int k = 0; k < 4; ++k) w += V[i][k] * V[j][k] * isq[k];
            Wd[i][j] = w;
            wo[i * 4 + j] = (float)w;
        }
    }
    #pragma unroll
    for (int i = 0; i < 4; ++i) {
        double wmI = Wd[i][0]*m[0] + Wd[i][1]*m[1] + Wd[i][2]*m[2] + Wd[i][3]*m[3];
        wo[16 + i] = (float)(-wmI);   // negWm
        wo[20 + i] = (float)m[i];
    }
}

// ---------------- Stage 3: apply out_i = sum_j W_ij x_j - (W m)_i ----
__global__ __launch_bounds__(256) void wh_apply(const float* __restrict__ x,
                                                const float* __restrict__ wm,
                                                float* __restrict__ out) {
    const int blk = blockIdx.x;
    const int b = blk >> 6;
    const int g = blk & 63;
    const int tid = threadIdx.x;

    __shared__ float sW[20];
    if (tid < 20) sW[tid] = wm[g * 24 + tid];
    __syncthreads();

    float W[4][4], nwm[4];
    #pragma unroll
    for (int i = 0; i < 4; ++i) {
        #pragma unroll
        for (int j = 0; j < 4; ++j) W[i][j] = sW[i * 4 + j];
        nwm[i] = sW[16 + i];
    }

    const size_t off = (size_t)b * ((size_t)NFEAT * WH) + (size_t)g * (GS * WH);
    const vf4* __restrict__ xin = (const vf4*)(x + off);
    vf4* __restrict__ o = (vf4*)(out + off);

#define APPLY4(q)                                                              \
    {                                                                          \
        vf4 v0 = xin[(q)];                                                     \
        vf4 v1 = xin[(q) + PLANEQ];                                            \
        vf4 v2 = xin[(q) + 2 * PLANEQ];                                        \
        vf4 v3 = xin[(q) + 3 * PLANEQ];                                        \
        _Pragma("unroll")                                                      \
        for (int i = 0; i < 4; ++i) {                                          \
            vf4 r;                                                             \
            _Pragma("unroll")                                                  \
            for (int k = 0; k < 4; ++k) {                                      \
                r[k] = fmaf(W[i][0], v0[k],                                    \
                       fmaf(W[i][1], v1[k],                                    \
                       fmaf(W[i][2], v2[k],                                    \
                       fmaf(W[i][3], v3[k], nwm[i]))));                        \
            }                                                                  \
            __builtin_nontemporal_store(r, &o[(q) + i * PLANEQ]);              \
        }                                                                      \
    }

    APPLY4(tid);
    APPLY4(tid + 256);
    APPLY4(tid + 512);
    if (tid < PLANEQ - 768) APPLY4(tid + 768);
#undef APPLY4
}

extern "C" void kernel_launch(void* const* d_in, const int* in_sizes, int n_in,
                              void* d_out, int out_size, void* d_ws, size_t ws_size,
                              hipStream_t stream) {
    const float* x = (const float*)d_in[0];
    float* out = (float*)d_out;

    float* partials = (float*)d_ws;                          // 64*64*16 f = 256 KiB
    float* wm       = partials + (size_t)NG * BATCH * PREC;  // 64*24 f
    int*   cnt      = (int*)(wm + NG * 24);                  // 64 ints

    hipMemsetAsync(cnt, 0, NG * sizeof(int), stream);
    wh_reduce_eigen<<<BATCH * NG, 256, 0, stream>>>(x, partials, wm, cnt);
    wh_apply<<<BATCH * NG, 256, 0, stream>>>(x, wm, out);
}

// Round 5
// 110.285 us; speedup vs baseline: 3.5805x; 3.5805x over previous
//
#include <hip/hip_runtime.h>
#include <math.h>

#define BATCH   64
#define NFEAT   256
#define GS      4
#define NG      64
#define WH      3136            // 56*56
#define PLANEQ  784             // WH/4 (float4 quads per channel plane)
#define NTOT    (BATCH*WH)      // 200704 samples per channel
#define EPSV    1e-3
#define PREC    16              // padded floats per partial record

typedef float vf4 __attribute__((ext_vector_type(4)));

// ---------------- Stage 1: per-(b,g) partial sums ----------------
//   q 0..3  = sum x_i ; q 4..13 = sum x_i x_j (i<=j)
// partials[(g*64+b)*16 + q]. Deterministic, no atomics, no fences.
__global__ __launch_bounds__(256) void wh_reduce(const float* __restrict__ x,
                                                 float* __restrict__ partials) {
    const int blk = blockIdx.x;
    const int b = blk >> 6;
    const int g = blk & 63;
    const int tid = threadIdx.x;
    const vf4* __restrict__ xin =
        (const vf4*)(x + (size_t)b * ((size_t)NFEAT * WH) + (size_t)g * (GS * WH));

    // 3 full rounds + 16-thread tail; 12 loads issued back-to-back.
    vf4 a0 = xin[tid];             vf4 a1 = xin[tid + 256];             vf4 a2 = xin[tid + 512];
    vf4 b0 = xin[PLANEQ + tid];    vf4 b1 = xin[PLANEQ + tid + 256];    vf4 b2 = xin[PLANEQ + tid + 512];
    vf4 c0 = xin[2*PLANEQ + tid];  vf4 c1 = xin[2*PLANEQ + tid + 256];  vf4 c2 = xin[2*PLANEQ + tid + 512];
    vf4 d0 = xin[3*PLANEQ + tid];  vf4 d1 = xin[3*PLANEQ + tid + 256];  vf4 d2 = xin[3*PLANEQ + tid + 512];

    float s0=0.f,s1=0.f,s2=0.f,s3=0.f;
    float p0=0.f,p1=0.f,p2=0.f,p3=0.f,p4=0.f,p5=0.f,p6=0.f,p7=0.f,p8=0.f,p9=0.f;

#define ACC4(va, vb, vc, vd)                                         \
    {                                                                \
        _Pragma("unroll")                                            \
        for (int k = 0; k < 4; ++k) {                                \
            float A = (va)[k], B = (vb)[k], C = (vc)[k], D = (vd)[k];\
            s0 += A; s1 += B; s2 += C; s3 += D;                      \
            p0 = fmaf(A, A, p0);  p1 = fmaf(A, B, p1);               \
            p2 = fmaf(A, C, p2);  p3 = fmaf(A, D, p3);               \
            p4 = fmaf(B, B, p4);  p5 = fmaf(B, C, p5);               \
            p6 = fmaf(B, D, p6);  p7 = fmaf(C, C, p7);               \
            p8 = fmaf(C, D, p8);  p9 = fmaf(D, D, p9);               \
        }                                                            \
    }

    ACC4(a0, b0, c0, d0);
    ACC4(a1, b1, c1, d1);
    ACC4(a2, b2, c2, d2);
    if (tid < PLANEQ - 768) {   // 16 tail quads
        vf4 at = xin[768 + tid];
        vf4 bt = xin[PLANEQ + 768 + tid];
        vf4 ct = xin[2*PLANEQ + 768 + tid];
        vf4 dt = xin[3*PLANEQ + 768 + tid];
        ACC4(at, bt, ct, dt);
    }
#undef ACC4

    float vals[14] = {s0,s1,s2,s3,p0,p1,p2,p3,p4,p5,p6,p7,p8,p9};
    #pragma unroll
    for (int q = 0; q < 14; ++q) {
        float v = vals[q];
        #pragma unroll
        for (int off = 32; off > 0; off >>= 1) v += __shfl_down(v, off, 64);
        vals[q] = v;
    }

    __shared__ float lds[4][14];
    const int wave = tid >> 6;
    const int lane = tid & 63;
    if (lane == 0) {
        #pragma unroll
        for (int q = 0; q < 14; ++q) lds[wave][q] = vals[q];
    }
    __syncthreads();
    if (tid < 14) {
        float v = lds[0][tid] + lds[1][tid] + lds[2][tid] + lds[3][tid];
        partials[((size_t)(g * BATCH + b)) * PREC + tid] = v;
    }
}

// ---------------- Stage 2: per-group eigen solve ----------------
// One block per group, 64 threads: butterfly-sum partials in double,
// lane 0 runs tolerance-early-exit Jacobi. Writes wm[g*24]:
//   0..15 = W,  16..19 = -W m,  20..23 = m
__global__ __launch_bounds__(64) void wh_eigen(const float* __restrict__ partials,
                                               float* __restrict__ wm) {
    const int g = blockIdx.x;
    const int b = threadIdx.x;

    const float* base = partials + ((size_t)(g * BATCH + b)) * PREC;
    double acc[14];
    #pragma unroll
    for (int q = 0; q < 14; ++q) acc[q] = (double)base[q];

    #pragma unroll
    for (int off = 32; off > 0; off >>= 1) {
        #pragma unroll
        for (int q = 0; q < 14; ++q) acc[q] += __shfl_xor(acc[q], off, 64);
    }

    if (b != 0) return;

    const double n = (double)NTOT;
    double m[4];
    #pragma unroll
    for (int i = 0; i < 4; ++i) m[i] = acc[i] / n;

    const int pi[10] = {0,0,0,0,1,1,1,2,2,3};
    const int pj[10] = {0,1,2,3,1,2,3,2,3,3};

    double A[4][4];
    #pragma unroll
    for (int t = 0; t < 10; ++t) {
        double cov = acc[4 + t] - n * m[pi[t]] * m[pj[t]];
        double v = (1.0 - EPSV) * cov + ((pi[t] == pj[t]) ? EPSV : 0.0);
        A[pi[t]][pj[t]] = v;
        A[pj[t]][pi[t]] = v;
    }

    double V[4][4] = {{1,0,0,0},{0,1,0,0},{0,0,1,0},{0,0,0,1}};

    const double tr = A[0][0] + A[1][1] + A[2][2] + A[3][3];
    const double tol = 1e-26 * tr * tr + 1e-300;

    const int rp[6] = {0,0,0,1,1,2};
    const int rq[6] = {1,2,3,2,3,3};

    for (int sweep = 0; sweep < 10; ++sweep) {
        double off = 0.0;
        #pragma unroll
        for (int t = 0; t < 6; ++t) off += A[rp[t]][rq[t]] * A[rp[t]][rq[t]];
        if (off < tol) break;

        #pragma unroll
        for (int t = 0; t < 6; ++t) {
            const int p = rp[t], q = rq[t];
            double apq = A[p][q];
            if (apq * apq < 1e-60) continue;
            double theta = (A[q][q] - A[p][p]) / (2.0 * apq);
            double tt = ((theta >= 0.0) ? 1.0 : -1.0) /
                        (fabs(theta) + sqrt(theta * theta + 1.0));
            double c = 1.0 / sqrt(tt * tt + 1.0);
            double s = tt * c;
            #pragma unroll
            for (int k = 0; k < 4; ++k) {
                double akp = A[k][p], akq = A[k][q];
                A[k][p] = c * akp - s * akq;
                A[k][q] = s * akp + c * akq;
            }
            #pragma unroll
            for (int k = 0; k < 4; ++k) {
                double apk = A[p][k], aqk = A[q][k];
                A[p][k] = c * apk - s * aqk;
                A[q][k] = s * apk + c * aqk;
            }
            #pragma unroll
            for (int k = 0; k < 4; ++k) {
                double vkp = V[k][p], vkq = V[k][q];
                V[k][p] = c * vkp - s * vkq;
                V[k][q] = s * vkp + c * vkq;
            }
        }
    }

    double isq[4];
    #pragma unroll
    for (int k = 0; k < 4; ++k) isq[k] = 1.0 / sqrt(A[k][k] + EPSV);

    float* wo = wm + g * 24;
    double Wd[4][4];
    #pragma unroll
    for (int i = 0; i < 4; ++i) {
        #pragma unroll
        for (int j = 0; j < 4; ++j) {
            double w = 0.0;
            #pragma unroll
            for (int k = 0; k < 4; ++k) w += V[i][k] * V[j][k] * isq[k];
            Wd[i][j] = w;
            wo[i * 4 + j] = (float)w;
        }
    }
    #pragma unroll
    for (int i = 0; i < 4; ++i) {
        double wmI = Wd[i][0]*m[0] + Wd[i][1]*m[1] + Wd[i][2]*m[2] + Wd[i][3]*m[3];
        wo[16 + i] = (float)(-wmI);   // -W m
        wo[20 + i] = (float)m[i];
    }
}

// ---------------- Stage 3: apply out_i = sum_j W_ij x_j + (-W m)_i ----
__global__ __launch_bounds__(256) void wh_apply(const float* __restrict__ x,
                                                const float* __restrict__ wm,
                                                float* __restrict__ out) {
    const int blk = blockIdx.x;
    const int b = blk >> 6;
    const int g = blk & 63;
    const int tid = threadIdx.x;

    __shared__ float sW[20];
    if (tid < 20) sW[tid] = wm[g * 24 + tid];
    __syncthreads();

    float W[4][4], nwm[4];
    #pragma unroll
    for (int i = 0; i < 4; ++i) {
        #pragma unroll
        for (int j = 0; j < 4; ++j) W[i][j] = sW[i * 4 + j];
        nwm[i] = sW[16 + i];
    }

    const size_t off = (size_t)b * ((size_t)NFEAT * WH) + (size_t)g * (GS * WH);
    const vf4* __restrict__ xin = (const vf4*)(x + off);
    vf4* __restrict__ o = (vf4*)(out + off);

#define APPLY4(q)                                                              \
    {                                                                          \
        vf4 v0 = xin[(q)];                                                     \
        vf4 v1 = xin[(q) + PLANEQ];                                            \
        vf4 v2 = xin[(q) + 2 * PLANEQ];                                        \
        vf4 v3 = xin[(q) + 3 * PLANEQ];                                        \
        _Pragma("unroll")                                                      \
        for (int i = 0; i < 4; ++i) {                                          \
            vf4 r;                                                             \
            _Pragma("unroll")                                                  \
            for (int k = 0; k < 4; ++k) {                                      \
                r[k] = fmaf(W[i][0], v0[k],                                    \
                       fmaf(W[i][1], v1[k],                                    \
                       fmaf(W[i][2], v2[k],                                    \
                       fmaf(W[i][3], v3[k], nwm[i]))));                        \
            }                                                                  \
            __builtin_nontemporal_store(r, &o[(q) + i * PLANEQ]);              \
        }                                                                      \
    }

    APPLY4(tid);
    APPLY4(tid + 256);
    APPLY4(tid + 512);
    if (tid < PLANEQ - 768) APPLY4(tid + 768);
#undef APPLY4
}

extern "C" void kernel_launch(void* const* d_in, const int* in_sizes, int n_in,
                              void* d_out, int out_size, void* d_ws, size_t ws_size,
                              hipStream_t stream) {
    const float* x = (const float*)d_in[0];
    float* out = (float*)d_out;

    float* partials = (float*)d_ws;                          // 64*64*16 f = 256 KiB
    float* wm       = partials + (size_t)NG * BATCH * PREC;  // 64*24 f

    wh_reduce<<<BATCH * NG, 256, 0, stream>>>(x, partials);
    wh_eigen<<<NG, 64, 0, stream>>>(partials, wm);
    wh_apply<<<BATCH * NG, 256, 0, stream>>>(x, wm, out);
}